// Round 11
// baseline (1276.979 us; speedup 1.0000x reference)
//
#include <hip/hip_runtime.h>
#include <math.h>

#define G_   8
#define NPG_ 4096
#define HC_  16
#define LAT_ 64
#define FF_  512
#define EDIM_ 3
#define EH_  64
#define NN_  32768
#define EE_  393216
#define EPAD_ (EE_ + NN_ + 8)   // max padded edge slots (pad each node to even)

typedef float v2f __attribute__((ext_vector_type(2)));
typedef float v4f __attribute__((ext_vector_type(4)));

#if __has_builtin(__builtin_elementwise_fma) && __has_builtin(__builtin_elementwise_max)
static __device__ __forceinline__ v2f pkfma2(v2f a, v2f b, v2f c) {
  return __builtin_elementwise_fma(a, b, c);
}
static __device__ __forceinline__ v2f pkmax2(v2f a, v2f b) {
  return __builtin_elementwise_max(a, b);
}
#else
static __device__ __forceinline__ v2f pkfma2(v2f a, v2f b, v2f c) {
  v2f r; r.x = fmaf(a.x, b.x, c.x); r.y = fmaf(a.y, b.y, c.y); return r;
}
static __device__ __forceinline__ v2f pkmax2(v2f a, v2f b) {
  v2f r; r.x = fmaxf(a.x, b.x); r.y = fmaxf(a.y, b.y); return r;
}
#endif

// ---------------- front-end ----------------
__global__ void k_front1(const float* __restrict__ x, const float* __restrict__ w,
                         const float* __restrict__ b, float* __restrict__ h1) {
  int c = blockIdx.x * blockDim.x + threadIdx.x;
  if (c >= FF_) return;
  float acc[G_];
#pragma unroll
  for (int g = 0; g < G_; g++) acc[g] = 0.f;
  for (int r = 0; r < LAT_; r++) {
    float wv = w[r * FF_ + c];
#pragma unroll
    for (int g = 0; g < G_; g++) acc[g] = fmaf(x[g * LAT_ + r], wv, acc[g]);
  }
#pragma unroll
  for (int g = 0; g < G_; g++) h1[g * FF_ + c] = acc[g] + b[c];
}

__global__ __launch_bounds__(512) void k_front2(const float* __restrict__ h1,
                                                const float* __restrict__ w,
                                                const float* __restrict__ b,
                                                float* __restrict__ hn) {
  __shared__ float sh[G_ * FF_];
  for (int i = threadIdx.x; i < G_ * FF_; i += blockDim.x) sh[i] = h1[i];
  __syncthreads();
  int g = threadIdx.x >> 6;
  int lane = threadIdx.x & 63;
  int c = blockIdx.x * 64 + lane;
  const float* shg = &sh[g * FF_];
  float acc = 0.f;
#pragma unroll 8
  for (int r = 0; r < FF_; r++) acc = fmaf(shg[r], w[r * (NPG_ * HC_) + c], acc);
  float v = acc + b[c];
  hn[g * (NPG_ * HC_) + c] = v > 0.f ? v : expm1f(v);
}

// ---------------- counting sort by src (ranges padded to even) ----------------
__global__ void k_zero(int* __restrict__ p, int nv) {
  int i = blockIdx.x * blockDim.x + threadIdx.x;
  if (i < nv) p[i] = 0;
}
__global__ void k_hist(const int* __restrict__ key, int* __restrict__ cnt) {
  int e = blockIdx.x * blockDim.x + threadIdx.x;
  if (e < EE_) atomicAdd(&cnt[key[e]], 1);
}
// prefix over even-rounded counts
__global__ __launch_bounds__(1024) void k_scan(const int* __restrict__ cnt,
                                               int* __restrict__ rowptr,
                                               int* __restrict__ cursor) {
  __shared__ int part[1024];
  int t = threadIdx.x;
  int base = t * 32;
  int loc[32];
  int s = 0;
#pragma unroll
  for (int i = 0; i < 32; i++) {
    loc[i] = s;
    s += (cnt[base + i] + 1) & ~1;
  }
  part[t] = s;
  __syncthreads();
  for (int off = 1; off < 1024; off <<= 1) {
    int v = (t >= off) ? part[t - off] : 0;
    __syncthreads();
    part[t] += v;
    __syncthreads();
  }
  int pre = (t == 0) ? 0 : part[t - 1];
#pragma unroll
  for (int i = 0; i < 32; i++) {
    int v = pre + loc[i];
    rowptr[base + i] = v;
    cursor[base + i] = v;
  }
  if (t == 1023) rowptr[NN_] = part[1023];
}
// prefill pair records with zero-attr edges pointing at the dummy row NN_
__global__ void k_pfill(float4* __restrict__ pairb) {
  int p = blockIdx.x * blockDim.x + threadIdx.x;
  if (p >= EPAD_ / 2) return;
  float df = __int_as_float(NN_);
  pairb[p * 2]     = make_float4(0.f, 0.f, 0.f, 0.f);
  pairb[p * 2 + 1] = make_float4(0.f, 0.f, df, df);
}
// scatter edge attrs into padded src-sorted pair records:
// pair p, slot s: floats [p*8+s]=x, [p*8+2+s]=y, [p*8+4+s]=z, [p*8+6+s]=dst
__global__ void k_scatter(const int* __restrict__ src, const int* __restrict__ dst,
                          const float* __restrict__ ea, int* __restrict__ cursor,
                          float* __restrict__ pairb) {
  int e = blockIdx.x * blockDim.x + threadIdx.x;
  if (e >= EE_) return;
  int pos = atomicAdd(&cursor[src[e]], 1);
  int b = (pos >> 1) * 8 + (pos & 1);
  pairb[b]     = ea[e * 3];
  pairb[b + 2] = ea[e * 3 + 1];
  pairb[b + 4] = ea[e * 3 + 2];
  pairb[b + 6] = __int_as_float(dst[e]);
}

// ---------------- per-conv kernels ----------------
__global__ void k_nodeinit(const float* __restrict__ hn, const float* __restrict__ root,
                           const float* __restrict__ bias, float* __restrict__ out) {
  int idx = blockIdx.x * blockDim.x + threadIdx.x;
  if (idx >= NN_ * HC_) return;
  int nd = idx >> 4, o = idx & 15;
  float acc = bias[o];
#pragma unroll
  for (int i = 0; i < 16; i++) acc = fmaf(hn[nd * 16 + i], root[i * 16 + o], acc);
  out[idx] = acc;
}

// W2m lane-fast: W2m[i*1024 + j4*256 + l*4 + c] = w2[h*256 + i*16 + o],
//   h=(l>>4)*16 + j4*4 + c, o=l&15.  w1p4[h] = (w1[0..2][h], b1[h])
__global__ void k_wprep(const float* __restrict__ w2, const float* __restrict__ w1,
                        const float* __restrict__ b1, float* __restrict__ W2m,
                        float4* __restrict__ w1p4) {
  int idx = blockIdx.x * 256 + threadIdx.x;
  if (idx < 16384) {
    int i  = idx >> 10;
    int j4 = (idx >> 8) & 3;
    int l  = (idx >> 2) & 63;
    int c  = idx & 3;
    int q = l >> 4, o = l & 15;
    int h = q * 16 + j4 * 4 + c;
    W2m[idx] = w2[h * 256 + i * 16 + o];
  }
  if (idx < 64) {
    w1p4[idx] = make_float4(w1[idx], w1[64 + idx], w1[128 + idx], b1[idx]);
  }
}

// Precompute per-node message matrices (proven R9 form):
// Mbuf[n*1024 + j4*256 + l*4 + c] = sum_i x_n[i]*W2m[i*1024 + j4*256 + l*4 + c]
__global__ __launch_bounds__(256, 4) void k_precM(
    const float* __restrict__ hn, const float* __restrict__ W2m,
    float4* __restrict__ Mbuf4) {
  int tid = threadIdx.x;
  int wave = tid >> 6, l = tid & 63;
  int n0 = (blockIdx.x * 4 + wave) * 4;
  const float4* __restrict__ W2m4 = (const float4*)W2m;

  float4 a0[4], a1[4], a2[4], a3[4];
#pragma unroll
  for (int j4 = 0; j4 < 4; j4++) {
    a0[j4] = make_float4(0.f, 0.f, 0.f, 0.f);
    a1[j4] = make_float4(0.f, 0.f, 0.f, 0.f);
    a2[j4] = make_float4(0.f, 0.f, 0.f, 0.f);
    a3[j4] = make_float4(0.f, 0.f, 0.f, 0.f);
  }
  for (int i = 0; i < 16; i++) {
    float x0 = hn[(n0 + 0) * 16 + i];
    float x1 = hn[(n0 + 1) * 16 + i];
    float x2 = hn[(n0 + 2) * 16 + i];
    float x3 = hn[(n0 + 3) * 16 + i];
#pragma unroll
    for (int j4 = 0; j4 < 4; j4++) {
      float4 w = W2m4[i * 256 + j4 * 64 + l];
      a0[j4].x = fmaf(x0, w.x, a0[j4].x); a0[j4].y = fmaf(x0, w.y, a0[j4].y);
      a0[j4].z = fmaf(x0, w.z, a0[j4].z); a0[j4].w = fmaf(x0, w.w, a0[j4].w);
      a1[j4].x = fmaf(x1, w.x, a1[j4].x); a1[j4].y = fmaf(x1, w.y, a1[j4].y);
      a1[j4].z = fmaf(x1, w.z, a1[j4].z); a1[j4].w = fmaf(x1, w.w, a1[j4].w);
      a2[j4].x = fmaf(x2, w.x, a2[j4].x); a2[j4].y = fmaf(x2, w.y, a2[j4].y);
      a2[j4].z = fmaf(x2, w.z, a2[j4].z); a2[j4].w = fmaf(x2, w.w, a2[j4].w);
      a3[j4].x = fmaf(x3, w.x, a3[j4].x); a3[j4].y = fmaf(x3, w.y, a3[j4].y);
      a3[j4].z = fmaf(x3, w.z, a3[j4].z); a3[j4].w = fmaf(x3, w.w, a3[j4].w);
    }
  }
  int s0 = n0 * 256;
#pragma unroll
  for (int j4 = 0; j4 < 4; j4++) Mbuf4[s0 + j4 * 64 + l] = a0[j4];
#pragma unroll
  for (int j4 = 0; j4 < 4; j4++) Mbuf4[s0 + 256 + j4 * 64 + l] = a1[j4];
#pragma unroll
  for (int j4 = 0; j4 < 4; j4++) Mbuf4[s0 + 512 + j4 * 64 + l] = a2[j4];
#pragma unroll
  for (int j4 = 0; j4 < 4; j4++) Mbuf4[s0 + 768 + j4 * 64 + l] = a3[j4];
}

// Edge aggregation. One wave per source node, no LDS. R9 structure; the j-loop
// runs packed fp32 (v_pk_fma_f32) over edge PAIRS stored as pair records, so
// v2f operands come straight from float4 loads (no marshaling movs).
__global__ __launch_bounds__(256, 4) void k_edge(
    const float* __restrict__ hn, const int* __restrict__ rowptr,
    const v4f* __restrict__ pairb, const float4* __restrict__ w1p4,
    const float* __restrict__ b2, const float4* __restrict__ Mbuf4,
    float* __restrict__ hnext) {
  int tid = threadIdx.x;
  int wave = tid >> 6, l = tid & 63;
  int o = l & 15, q = l >> 4;
  int n = blockIdx.x * 4 + wave;

  int rs = rowptr[n], re = rowptr[n + 1];   // even-padded range
  if (rs >= re) return;

  int mb = n * 256 + l;
  float4 m0 = Mbuf4[mb], m1 = Mbuf4[mb + 64], m2 = Mbuf4[mb + 128],
         m3 = Mbuf4[mb + 192];
  float M[16] = {m0.x, m0.y, m0.z, m0.w, m1.x, m1.y, m1.z, m1.w,
                 m2.x, m2.y, m2.z, m2.w, m3.x, m3.y, m3.z, m3.w};

  const float4* __restrict__ hx4 = (const float4*)&hn[n * 16];
  float T = 0.f;
#pragma unroll
  for (int i4 = 0; i4 < 4; i4++) {
    float4 xq = hx4[i4];
    T = fmaf(xq.x, b2[(i4 * 4 + 0) * 16 + o], T);
    T = fmaf(xq.y, b2[(i4 * 4 + 1) * 16 + o], T);
    T = fmaf(xq.z, b2[(i4 * 4 + 2) * 16 + o], T);
    T = fmaf(xq.w, b2[(i4 * 4 + 3) * 16 + o], T);
  }

  const float4* __restrict__ w1v = &w1p4[q * 16];

  // slots: edges k,k+1 in {pairb[k], pairb[k+1]}, edges k+2,k+3 in {[k+2],[k+3]}
  v4f c0 = pairb[rs], c1 = pairb[rs + 1], c2 = pairb[rs + 2], c3 = pairb[rs + 3];
  for (int k = rs; k < re; k += 4) {
    v4f n0 = pairb[k + 4], n1 = pairb[k + 5], n2 = pairb[k + 6], n3 = pairb[k + 7];

    v2f eXa = __builtin_shufflevector(c0, c0, 0, 1);
    v2f eYa = __builtin_shufflevector(c0, c0, 2, 3);
    v2f eZa = __builtin_shufflevector(c1, c1, 0, 1);
    v2f eXb = __builtin_shufflevector(c2, c2, 0, 1);
    v2f eYb = __builtin_shufflevector(c2, c2, 2, 3);
    v2f eZb = __builtin_shufflevector(c3, c3, 0, 1);
    v2f pA = {0.f, 0.f}, pB = {0.f, 0.f};
    v2f z2 = {0.f, 0.f};
#pragma unroll
    for (int j = 0; j < 16; j++) {
      float4 wv = w1v[j];
      v2f wx = {wv.x, wv.x};
      v2f wy = {wv.y, wv.y};
      v2f wz = {wv.z, wv.z};
      v2f wc = {wv.w, wv.w};
      v2f m2v = {M[j], M[j]};
      v2f hA = pkmax2(pkfma2(eZa, wz, pkfma2(eYa, wy, pkfma2(eXa, wx, wc))), z2);
      v2f hB = pkmax2(pkfma2(eZb, wz, pkfma2(eYb, wy, pkfma2(eXb, wx, wc))), z2);
      pA = pkfma2(hA, m2v, pA);
      pB = pkfma2(hB, m2v, pB);
    }
    float p0 = pA.x, p1 = pA.y, p2 = pB.x, p3 = pB.y;
    p0 += __shfl_xor(p0, 16); p1 += __shfl_xor(p1, 16);
    p2 += __shfl_xor(p2, 16); p3 += __shfl_xor(p3, 16);
    p0 += __shfl_xor(p0, 32); p1 += __shfl_xor(p1, 32);
    p2 += __shfl_xor(p2, 32); p3 += __shfl_xor(p3, 32);

    // lane group q commits edge k+q; pads go to dummy row NN_.
    float vv  = (q == 0) ? p0 : (q == 1) ? p1 : (q == 2) ? p2 : p3;
    float dpf = (q == 0) ? c1[2] : (q == 1) ? c1[3] : (q == 2) ? c3[2] : c3[3];
    if (k + q < re) atomicAdd(&hnext[__float_as_int(dpf) * 16 + o], vv + T);

    c0 = n0; c1 = n1; c2 = n2; c3 = n3;
  }
}

__global__ void k_elu(const float* __restrict__ in, float* __restrict__ out) {
  int idx = blockIdx.x * blockDim.x + threadIdx.x;
  if (idx >= NN_ * HC_) return;
  float v = in[idx];
  out[idx] = v > 0.f ? v : expm1f(v);
}

// ---------------- launch ----------------
extern "C" void kernel_launch(void* const* d_in, const int* in_sizes, int n_in,
                              void* d_out, int out_size, void* d_ws, size_t ws_size,
                              hipStream_t stream) {
  const float* x    = (const float*)d_in[0];
  const int*   ei   = (const int*)d_in[1];
  const float* ea   = (const float*)d_in[2];
  const float* fc2w = (const float*)d_in[3];
  const float* fc2b = (const float*)d_in[4];
  const float* fc1w = (const float*)d_in[5];
  const float* fc1b = (const float*)d_in[6];
  float* out = (float*)d_out;

  float* ws = (float*)d_ws;
  float*  h1     = ws;                               // 4096
  float*  hnode  = h1 + 4096;                        // N*16
  float*  hnext  = hnode + (size_t)NN_ * HC_;        // N*16 + 16 (dummy row)
  float*  W2m    = hnext + (size_t)NN_ * HC_ + 16;   // 16384
  float4* w1p4   = (float4*)(W2m + 16384);           // 256 floats
  float*  pairb  = (float*)w1p4 + 256;               // EPAD_*4 floats
  float4* Mbuf4  = (float4*)(pairb + (size_t)EPAD_ * 4);  // N*1024 floats
  int*    cnt    = (int*)((float*)Mbuf4 + (size_t)NN_ * 1024);
  int*    rowptr = cnt + NN_;
  int*    cursor = rowptr + NN_ + 1;

  const int* src  = ei;
  const int* dstp = ei + EE_;

  k_front1<<<2, 256, 0, stream>>>(x, fc2w, fc2b, h1);
  k_front2<<<1024, 512, 0, stream>>>(h1, fc1w, fc1b, hnode);

  k_zero<<<(NN_ + 255) / 256, 256, 0, stream>>>(cnt, NN_);
  k_hist<<<(EE_ + 255) / 256, 256, 0, stream>>>(src, cnt);
  k_scan<<<1, 1024, 0, stream>>>(cnt, rowptr, cursor);
  k_pfill<<<(EPAD_ / 2 + 255) / 256, 256, 0, stream>>>((float4*)pairb);
  k_scatter<<<(EE_ + 255) / 256, 256, 0, stream>>>(src, dstp, ea, cursor, pairb);

  for (int cv = 0; cv < 2; cv++) {
    const float* root = (const float*)d_in[7 + cv * 6];
    const float* cb   = (const float*)d_in[8 + cv * 6];
    const float* w1   = (const float*)d_in[9 + cv * 6];
    const float* b1   = (const float*)d_in[10 + cv * 6];
    const float* w2   = (const float*)d_in[11 + cv * 6];
    const float* b2   = (const float*)d_in[12 + cv * 6];
    k_wprep<<<64, 256, 0, stream>>>(w2, w1, b1, W2m, w1p4);
    k_nodeinit<<<NN_ * HC_ / 256, 256, 0, stream>>>(hnode, root, cb, hnext);
    k_precM<<<NN_ / 16, 256, 0, stream>>>(hnode, W2m, Mbuf4);
    k_edge<<<NN_ / 4, 256, 0, stream>>>(hnode, rowptr, (const v4f*)pairb, w1p4,
                                        b2, Mbuf4, hnext);
    k_elu<<<NN_ * HC_ / 256, 256, 0, stream>>>(hnext, cv == 0 ? hnode : out);
  }
}

// Round 12
// 365.385 us; speedup vs baseline: 3.4949x; 3.4949x over previous
//
#include <hip/hip_runtime.h>
#include <math.h>

#define G_   8
#define NPG_ 4096
#define HC_  16
#define LAT_ 64
#define FF_  512
#define EDIM_ 3
#define EH_  64
#define NN_  32768
#define EE_  393216

// ---------------- front-end ----------------
__global__ void k_front1(const float* __restrict__ x, const float* __restrict__ w,
                         const float* __restrict__ b, float* __restrict__ h1) {
  int c = blockIdx.x * blockDim.x + threadIdx.x;
  if (c >= FF_) return;
  float acc[G_];
#pragma unroll
  for (int g = 0; g < G_; g++) acc[g] = 0.f;
  for (int r = 0; r < LAT_; r++) {
    float wv = w[r * FF_ + c];
#pragma unroll
    for (int g = 0; g < G_; g++) acc[g] = fmaf(x[g * LAT_ + r], wv, acc[g]);
  }
#pragma unroll
  for (int g = 0; g < G_; g++) h1[g * FF_ + c] = acc[g] + b[c];
}

__global__ __launch_bounds__(512) void k_front2(const float* __restrict__ h1,
                                                const float* __restrict__ w,
                                                const float* __restrict__ b,
                                                float* __restrict__ hn) {
  __shared__ float sh[G_ * FF_];
  for (int i = threadIdx.x; i < G_ * FF_; i += blockDim.x) sh[i] = h1[i];
  __syncthreads();
  int g = threadIdx.x >> 6;
  int lane = threadIdx.x & 63;
  int c = blockIdx.x * 64 + lane;
  const float* shg = &sh[g * FF_];
  float acc = 0.f;
#pragma unroll 8
  for (int r = 0; r < FF_; r++) acc = fmaf(shg[r], w[r * (NPG_ * HC_) + c], acc);
  float v = acc + b[c];
  hn[g * (NPG_ * HC_) + c] = v > 0.f ? v : expm1f(v);
}

// ---------------- counting sort by src ----------------
__global__ void k_zero(int* __restrict__ p, int nv) {
  int i = blockIdx.x * blockDim.x + threadIdx.x;
  if (i < nv) p[i] = 0;
}
__global__ void k_hist(const int* __restrict__ key, int* __restrict__ cnt) {
  int e = blockIdx.x * blockDim.x + threadIdx.x;
  if (e < EE_) atomicAdd(&cnt[key[e]], 1);
}
__global__ __launch_bounds__(1024) void k_scan(const int* __restrict__ cnt,
                                               int* __restrict__ rowptr,
                                               int* __restrict__ cursor) {
  __shared__ int part[1024];
  int t = threadIdx.x;
  int base = t * 32;
  int loc[32];
  int s = 0;
#pragma unroll
  for (int i = 0; i < 32; i++) { loc[i] = s; s += cnt[base + i]; }
  part[t] = s;
  __syncthreads();
  for (int off = 1; off < 1024; off <<= 1) {
    int v = (t >= off) ? part[t - off] : 0;
    __syncthreads();
    part[t] += v;
    __syncthreads();
  }
  int pre = (t == 0) ? 0 : part[t - 1];
#pragma unroll
  for (int i = 0; i < 32; i++) {
    int v = pre + loc[i];
    rowptr[base + i] = v;
    cursor[base + i] = v;
  }
  if (t == 1023) rowptr[NN_] = part[1023];
}
// fused scatter+gather: place edge data directly at its src-sorted slot
__global__ void k_scatter(const int* __restrict__ src, const int* __restrict__ dst,
                          const float* __restrict__ ea, int* __restrict__ cursor,
                          float4* __restrict__ eas4) {
  int e = blockIdx.x * blockDim.x + threadIdx.x;
  if (e < EE_) {
    int pos = atomicAdd(&cursor[src[e]], 1);
    eas4[pos] = make_float4(ea[e * 3], ea[e * 3 + 1], ea[e * 3 + 2],
                            __int_as_float(dst[e]));
  } else if (e < EE_ + 8) {
    eas4[e] = make_float4(0.f, 0.f, 0.f, __int_as_float(0));
  }
}

// ---------------- per-conv kernels ----------------
__global__ void k_nodeinit(const float* __restrict__ hn, const float* __restrict__ root,
                           const float* __restrict__ bias, float* __restrict__ out) {
  int idx = blockIdx.x * blockDim.x + threadIdx.x;
  if (idx >= NN_ * HC_) return;
  int nd = idx >> 4, o = idx & 15;
  float acc = bias[o];
#pragma unroll
  for (int i = 0; i < 16; i++) acc = fmaf(hn[nd * 16 + i], root[i * 16 + o], acc);
  out[idx] = acc;
}

// W2m lane-fast: W2m[i*1024 + j4*256 + l*4 + c] = w2[h*256 + i*16 + o],
//   h=(l>>4)*16 + j4*4 + c, o=l&15.  w1p4[h] = (w1[0..2][h], b1[h])
__global__ void k_wprep(const float* __restrict__ w2, const float* __restrict__ w1,
                        const float* __restrict__ b1, float* __restrict__ W2m,
                        float4* __restrict__ w1p4) {
  int idx = blockIdx.x * 256 + threadIdx.x;
  if (idx < 16384) {
    int i  = idx >> 10;
    int j4 = (idx >> 8) & 3;
    int l  = (idx >> 2) & 63;
    int c  = idx & 3;
    int q = l >> 4, o = l & 15;
    int h = q * 16 + j4 * 4 + c;
    W2m[idx] = w2[h * 256 + i * 16 + o];
  }
  if (idx < 64) {
    w1p4[idx] = make_float4(w1[idx], w1[64 + idx], w1[128 + idx], b1[idx]);
  }
}

// Precompute per-node message matrices (proven R9 form):
// Mbuf[n*1024 + j4*256 + l*4 + c] = sum_i x_n[i]*W2m[i*1024 + j4*256 + l*4 + c]
__global__ __launch_bounds__(256, 4) void k_precM(
    const float* __restrict__ hn, const float* __restrict__ W2m,
    float4* __restrict__ Mbuf4) {
  int tid = threadIdx.x;
  int wave = tid >> 6, l = tid & 63;
  int n0 = (blockIdx.x * 4 + wave) * 4;
  const float4* __restrict__ W2m4 = (const float4*)W2m;

  float4 a0[4], a1[4], a2[4], a3[4];
#pragma unroll
  for (int j4 = 0; j4 < 4; j4++) {
    a0[j4] = make_float4(0.f, 0.f, 0.f, 0.f);
    a1[j4] = make_float4(0.f, 0.f, 0.f, 0.f);
    a2[j4] = make_float4(0.f, 0.f, 0.f, 0.f);
    a3[j4] = make_float4(0.f, 0.f, 0.f, 0.f);
  }
  for (int i = 0; i < 16; i++) {
    float x0 = hn[(n0 + 0) * 16 + i];
    float x1 = hn[(n0 + 1) * 16 + i];
    float x2 = hn[(n0 + 2) * 16 + i];
    float x3 = hn[(n0 + 3) * 16 + i];
#pragma unroll
    for (int j4 = 0; j4 < 4; j4++) {
      float4 w = W2m4[i * 256 + j4 * 64 + l];
      a0[j4].x = fmaf(x0, w.x, a0[j4].x); a0[j4].y = fmaf(x0, w.y, a0[j4].y);
      a0[j4].z = fmaf(x0, w.z, a0[j4].z); a0[j4].w = fmaf(x0, w.w, a0[j4].w);
      a1[j4].x = fmaf(x1, w.x, a1[j4].x); a1[j4].y = fmaf(x1, w.y, a1[j4].y);
      a1[j4].z = fmaf(x1, w.z, a1[j4].z); a1[j4].w = fmaf(x1, w.w, a1[j4].w);
      a2[j4].x = fmaf(x2, w.x, a2[j4].x); a2[j4].y = fmaf(x2, w.y, a2[j4].y);
      a2[j4].z = fmaf(x2, w.z, a2[j4].z); a2[j4].w = fmaf(x2, w.w, a2[j4].w);
      a3[j4].x = fmaf(x3, w.x, a3[j4].x); a3[j4].y = fmaf(x3, w.y, a3[j4].y);
      a3[j4].z = fmaf(x3, w.z, a3[j4].z); a3[j4].w = fmaf(x3, w.w, a3[j4].w);
    }
  }
  int s0 = n0 * 256;
#pragma unroll
  for (int j4 = 0; j4 < 4; j4++) Mbuf4[s0 + j4 * 64 + l] = a0[j4];
#pragma unroll
  for (int j4 = 0; j4 < 4; j4++) Mbuf4[s0 + 256 + j4 * 64 + l] = a1[j4];
#pragma unroll
  for (int j4 = 0; j4 < 4; j4++) Mbuf4[s0 + 512 + j4 * 64 + l] = a2[j4];
#pragma unroll
  for (int j4 = 0; j4 < 4; j4++) Mbuf4[s0 + 768 + j4 * 64 + l] = a3[j4];
}

// Edge aggregation (R9 structure). One wave per source node. The only change:
// w1p4 staged in 1KB LDS, j-loop reads it as a 16-lane broadcast ds_read_b128
// instead of re-loading 16 float4 from L1 every chunk (frees the VMEM pipe
// and kills the per-chunk waitcnt stall).
__global__ __launch_bounds__(256, 4) void k_edge(
    const float* __restrict__ hn, const int* __restrict__ rowptr,
    const float4* __restrict__ eas4, const float4* __restrict__ w1p4,
    const float* __restrict__ b2, const float4* __restrict__ Mbuf4,
    float* __restrict__ hnext) {
  __shared__ float4 sw1[64];
  int tid = threadIdx.x;
  if (tid < 64) sw1[tid] = w1p4[tid];
  __syncthreads();

  int wave = tid >> 6, l = tid & 63;
  int o = l & 15, q = l >> 4;
  int n = blockIdx.x * 4 + wave;

  int rs = rowptr[n], re = rowptr[n + 1];
  if (rs >= re) return;

  int mb = n * 256 + l;
  float4 m0 = Mbuf4[mb], m1 = Mbuf4[mb + 64], m2 = Mbuf4[mb + 128],
         m3 = Mbuf4[mb + 192];
  float M[16] = {m0.x, m0.y, m0.z, m0.w, m1.x, m1.y, m1.z, m1.w,
                 m2.x, m2.y, m2.z, m2.w, m3.x, m3.y, m3.z, m3.w};

  const float4* __restrict__ hx4 = (const float4*)&hn[n * 16];
  float T = 0.f;
#pragma unroll
  for (int i4 = 0; i4 < 4; i4++) {
    float4 xq = hx4[i4];
    T = fmaf(xq.x, b2[(i4 * 4 + 0) * 16 + o], T);
    T = fmaf(xq.y, b2[(i4 * 4 + 1) * 16 + o], T);
    T = fmaf(xq.z, b2[(i4 * 4 + 2) * 16 + o], T);
    T = fmaf(xq.w, b2[(i4 * 4 + 3) * 16 + o], T);
  }

  const float4* __restrict__ w1v = &sw1[q * 16];

  float4 c0 = eas4[rs], c1 = eas4[rs + 1], c2 = eas4[rs + 2], c3 = eas4[rs + 3];
  for (int k = rs; k < re; k += 4) {
    float4 n0 = eas4[k + 4], n1 = eas4[k + 5], n2 = eas4[k + 6], n3 = eas4[k + 7];

    float p0 = 0.f, p1 = 0.f, p2 = 0.f, p3 = 0.f;
#pragma unroll
    for (int j = 0; j < 16; j++) {
      float4 wv = w1v[j];
      float m = M[j];
      float h0 = fmaxf(fmaf(c0.z, wv.z, fmaf(c0.y, wv.y, fmaf(c0.x, wv.x, wv.w))), 0.f);
      float h1 = fmaxf(fmaf(c1.z, wv.z, fmaf(c1.y, wv.y, fmaf(c1.x, wv.x, wv.w))), 0.f);
      float h2 = fmaxf(fmaf(c2.z, wv.z, fmaf(c2.y, wv.y, fmaf(c2.x, wv.x, wv.w))), 0.f);
      float h3 = fmaxf(fmaf(c3.z, wv.z, fmaf(c3.y, wv.y, fmaf(c3.x, wv.x, wv.w))), 0.f);
      p0 = fmaf(h0, m, p0);
      p1 = fmaf(h1, m, p1);
      p2 = fmaf(h2, m, p2);
      p3 = fmaf(h3, m, p3);
    }
    p0 += __shfl_xor(p0, 16); p1 += __shfl_xor(p1, 16);
    p2 += __shfl_xor(p2, 16); p3 += __shfl_xor(p3, 16);
    p0 += __shfl_xor(p0, 32); p1 += __shfl_xor(p1, 32);
    p2 += __shfl_xor(p2, 32); p3 += __shfl_xor(p3, 32);

    // every lane holds all four reduced sums; lane group q commits edge k+q
    float vv  = (q == 0) ? p0   : (q == 1) ? p1   : (q == 2) ? p2   : p3;
    float dpf = (q == 0) ? c0.w : (q == 1) ? c1.w : (q == 2) ? c2.w : c3.w;
    if (k + q < re) atomicAdd(&hnext[__float_as_int(dpf) * 16 + o], vv + T);

    c0 = n0; c1 = n1; c2 = n2; c3 = n3;
  }
}

__global__ void k_elu(const float* __restrict__ in, float* __restrict__ out) {
  int idx = blockIdx.x * blockDim.x + threadIdx.x;
  if (idx >= NN_ * HC_) return;
  float v = in[idx];
  out[idx] = v > 0.f ? v : expm1f(v);
}

// ---------------- launch ----------------
extern "C" void kernel_launch(void* const* d_in, const int* in_sizes, int n_in,
                              void* d_out, int out_size, void* d_ws, size_t ws_size,
                              hipStream_t stream) {
  const float* x    = (const float*)d_in[0];
  const int*   ei   = (const int*)d_in[1];
  const float* ea   = (const float*)d_in[2];
  const float* fc2w = (const float*)d_in[3];
  const float* fc2b = (const float*)d_in[4];
  const float* fc1w = (const float*)d_in[5];
  const float* fc1b = (const float*)d_in[6];
  float* out = (float*)d_out;

  float* ws = (float*)d_ws;
  float*  h1     = ws;                               // 4096
  float*  hnode  = h1 + 4096;                        // N*16
  float*  hnext  = hnode + (size_t)NN_ * HC_;        // N*16
  float*  W2m    = hnext + (size_t)NN_ * HC_;        // 16384
  float4* w1p4   = (float4*)(W2m + 16384);           // 256 floats
  float4* eas4   = (float4*)((float*)w1p4 + 256);    // (E+8)*4 floats
  float4* Mbuf4  = (float4*)((float*)eas4 + (size_t)(EE_ + 8) * 4);  // N*1024
  int*    cnt    = (int*)((float*)Mbuf4 + (size_t)NN_ * 1024);
  int*    rowptr = cnt + NN_;
  int*    cursor = rowptr + NN_ + 1;

  const int* src  = ei;
  const int* dstp = ei + EE_;

  k_front1<<<2, 256, 0, stream>>>(x, fc2w, fc2b, h1);
  k_front2<<<1024, 512, 0, stream>>>(h1, fc1w, fc1b, hnode);

  k_zero<<<(NN_ + 255) / 256, 256, 0, stream>>>(cnt, NN_);
  k_hist<<<(EE_ + 255) / 256, 256, 0, stream>>>(src, cnt);
  k_scan<<<1, 1024, 0, stream>>>(cnt, rowptr, cursor);
  k_scatter<<<(EE_ + 8 + 255) / 256, 256, 0, stream>>>(src, dstp, ea, cursor, eas4);

  for (int cv = 0; cv < 2; cv++) {
    const float* root = (const float*)d_in[7 + cv * 6];
    const float* cb   = (const float*)d_in[8 + cv * 6];
    const float* w1   = (const float*)d_in[9 + cv * 6];
    const float* b1   = (const float*)d_in[10 + cv * 6];
    const float* w2   = (const float*)d_in[11 + cv * 6];
    const float* b2   = (const float*)d_in[12 + cv * 6];
    k_wprep<<<64, 256, 0, stream>>>(w2, w1, b1, W2m, w1p4);
    k_nodeinit<<<NN_ * HC_ / 256, 256, 0, stream>>>(hnode, root, cb, hnext);
    k_precM<<<NN_ / 16, 256, 0, stream>>>(hnode, W2m, Mbuf4);
    k_edge<<<NN_ / 4, 256, 0, stream>>>(hnode, rowptr, eas4, w1p4, b2, Mbuf4, hnext);
    k_elu<<<NN_ * HC_ / 256, 256, 0, stream>>>(hnext, cv == 0 ? hnode : out);
  }
}